// Round 18
// baseline (256.990 us; speedup 1.0000x reference)
//
#include <hip/hip_runtime.h>
#include <hip/hip_bf16.h>
#include <math.h>

#define NLAT 256
#define NLON 512
#define LMAX 256
#define MMAX 257
#define BC   128

#define X_ELEMS 33554432
#define W_ELEMS 33685504
#define W_BYTES (W_ELEMS * 4LL)

#define FM    288                      // padded m rows for F
#define F_BYTES  ((size_t)2*FM*512*2)                    // 589,824
#define A_BYTES  ((size_t)4*BC*MMAX*NLAT*2)              // 67,371,008
#define OUTS_BYTES ((size_t)MMAX*2*BC*LMAX*2)            // 33,685,504

typedef short bf16x8 __attribute__((ext_vector_type(8)));
typedef float f32x4  __attribute__((ext_vector_type(4)));

__device__ __forceinline__ unsigned int bfpack2(float a, float b) {
    unsigned short lo = __builtin_bit_cast(unsigned short, __float2bfloat16(a));
    unsigned short hi = __builtin_bit_cast(unsigned short, __float2bfloat16(b));
    return (unsigned int)lo | ((unsigned int)hi << 16);
}
__device__ __forceinline__ unsigned short bf16bits(float a) {
    return __builtin_bit_cast(unsigned short, __float2bfloat16(a));
}
__device__ __forceinline__ void gload16(const void* g, void* l) {
    __builtin_amdgcn_global_load_lds(
        (const __attribute__((address_space(1))) unsigned int*)g,
        (__attribute__((address_space(3))) unsigned int*)l, 16, 0, 0);
}

// ---------------------------------------------------------------------------
// K0: build DFT matrix F[o][mm][n] bf16, scale 2*pi/512 folded in.
// ---------------------------------------------------------------------------
__global__ __launch_bounds__(256) void f_init(unsigned short* __restrict__ F)
{
    int mm = blockIdx.x, o = blockIdx.y, t = threadIdx.x;
    const float s = 6.283185307179586f / 512.0f;
    for (int c = 0; c < 2; ++c) {
        int n = t * 2 + c;
        float val = 0.0f;
        if (mm < MMAX) {
            int j = (mm * n) & 511;
            float ang = 6.283185307179586f * (float)j / 512.0f;
            float sn, cs; __sincosf(ang, &sn, &cs);
            val = (o == 0) ? s * cs : -s * sn;
        }
        F[((size_t)o * FM + mm) * 512 + n] =
            __builtin_bit_cast(unsigned short, __float2bfloat16(val));
    }
}

// ---------------------------------------------------------------------------
// K1 v8: DFT via MFMA = v7 + xl/fl LDS OVERLAY (xl dead after barr hoist ->
// F dbuf reuses its 64KB). LDS 140.3KB -> 74.75KB -> 2 blocks/CU (4 w/SIMD).
// x staged coalesced -> LDS -> barr regs; F via global_load_lds dbuf;
// LDS-staged full-line stores. __launch_bounds__(512,1): no spill heuristic.
// grid (bcc:256, kq:4), 512 thr = 8 waves (o:2, kt:4).
// ---------------------------------------------------------------------------
__global__ __launch_bounds__(512, 1) void dft_mfma(const float* __restrict__ x,
                                                   const unsigned short* __restrict__ F,
                                                   unsigned short* __restrict__ aout)
{
    __shared__ __align__(16) unsigned char smem[65536];      // xl THEN fl[2][32768]
    __shared__ __align__(16) unsigned short st[2][32][72];   // D tile [2o x 16m][64k]
    unsigned char* xl = smem;
    unsigned char (*fl)[32768] = (unsigned char (*)[32768])smem;

    int bcc = blockIdx.x;           // 0..255
    int kq  = blockIdx.y;           // 0..3
    int bc = bcc >> 1, comp = bcc & 1;
    int t = threadIdx.x;
    int wid = t >> 6, lane = t & 63;

    // ---- stage x coalesced (proven v3-v7): wave w stages rows w*8+p
    {
        const float* xg = x + ((size_t)bcc * NLAT + kq * 64) * NLON;
        #pragma unroll
        for (int p = 0; p < 8; ++p) {
            int row = wid * 8 + p;
            const float* src = xg + (size_t)row * NLON + lane * 8;
            float4 f0 = *(const float4*)(src);
            float4 f1 = *(const float4*)(src + 4);
            uint4 v;
            v.x = bfpack2(f0.x, f0.y); v.y = bfpack2(f0.z, f0.w);
            v.z = bfpack2(f1.x, f1.y); v.w = bfpack2(f1.z, f1.w);
            unsigned off = ((unsigned)row * 1024u + (unsigned)lane * 16u)
                           ^ ((unsigned)(row & 15) << 4);
            *(uint4*)(xl + off) = v;
        }
    }
    __syncthreads();                // x staged

    int o = wid >> 2, kt = wid & 3;
    int r15 = lane & 15, hi = lane >> 4;
    int klocal = kt * 16 + r15;
    unsigned braw = (unsigned)klocal * 1024u;
    unsigned bswz = (unsigned)(klocal & 15) << 4;

    // ---- hoist B fragments LDS -> registers ONCE (xl dead afterwards)
    bf16x8 barr[16];
    #pragma unroll
    for (int nt = 0; nt < 16; ++nt) {
        unsigned c0 = (unsigned)(nt * 64 + hi * 16);
        barr[nt] = *(const bf16x8*)(xl + ((braw + c0) ^ bswz));
    }
    __syncthreads();                // all waves done reading xl; fl may overwrite

    // F tile staging via global_load_lds (LDS dest linear, global col
    // pre-swizzled — involution, validated v5-v7).
    const unsigned char* Fb = (const unsigned char*)F;
    unsigned gcol = ((unsigned)lane * 16u);

    #define STAGE_F(buf, mt)                                                  \
        {                                                                     \
            _Pragma("unroll")                                                 \
            for (int p = 0; p < 4; ++p) {                                     \
                int fr = wid * 4 + p;                                         \
                int o2 = fr >> 4, mr = fr & 15;                               \
                size_t grow = (size_t)o2 * FM + (mt) * 16 + mr;               \
                const void* g = Fb + grow * 1024u                             \
                                + (gcol ^ ((unsigned)(fr & 15) << 4));        \
                gload16(g, (unsigned char*)fl[buf] + (unsigned)fr * 1024u);   \
            }                                                                 \
        }

    STAGE_F(0, 0);
    __syncthreads();                // drains gload_lds for fl[0]

    unsigned arow = (unsigned)(o * 16 + r15);
    unsigned abase = arow * 1024u;
    unsigned aswz = (unsigned)r15 << 4;
    unsigned short* ao = aout;

    for (int mt = 0; mt < 17; ++mt) {
        int cur = mt & 1;
        if (mt < 16) STAGE_F(cur ^ 1, mt + 1);   // async, lands by next barrier

        const unsigned char* fb = fl[cur];
        f32x4 acc0 = {0.f,0.f,0.f,0.f}, acc1 = {0.f,0.f,0.f,0.f};
        f32x4 acc2 = {0.f,0.f,0.f,0.f}, acc3 = {0.f,0.f,0.f,0.f};
        #pragma unroll
        for (int nt = 0; nt < 16; nt += 4) {
            unsigned c0 = (unsigned)(nt * 64 + hi * 16);
            bf16x8 a0 = *(const bf16x8*)(fb + ((abase + c0)        ^ aswz));
            bf16x8 a1 = *(const bf16x8*)(fb + ((abase + c0 + 64u)  ^ aswz));
            bf16x8 a2 = *(const bf16x8*)(fb + ((abase + c0 + 128u) ^ aswz));
            bf16x8 a3 = *(const bf16x8*)(fb + ((abase + c0 + 192u) ^ aswz));
            acc0 = __builtin_amdgcn_mfma_f32_16x16x32_bf16(a0, barr[nt],     acc0, 0, 0, 0);
            acc1 = __builtin_amdgcn_mfma_f32_16x16x32_bf16(a1, barr[nt + 1], acc1, 0, 0, 0);
            acc2 = __builtin_amdgcn_mfma_f32_16x16x32_bf16(a2, barr[nt + 2], acc2, 0, 0, 0);
            acc3 = __builtin_amdgcn_mfma_f32_16x16x32_bf16(a3, barr[nt + 3], acc3, 0, 0, 0);
        }
        #pragma unroll
        for (int j = 0; j < 4; ++j)
            acc0[j] = (acc0[j] + acc1[j]) + (acc2[j] + acc3[j]);

        // stage D to LDS (row = o*16 + mm_local, col = klocal)
        {
            int rbase = o * 16 + hi * 4;
            #pragma unroll
            for (int j = 0; j < 4; ++j)
                st[cur][rbase + j][klocal] = bf16bits(acc0[j]);
        }
        __syncthreads();            // drains gload_lds(mt+1) + st writes

        // cooperative full-line store: 16 thr x 8B per (o,mm) row
        {
            int r = t >> 4, ch = t & 15;
            int mm = mt * 16 + (r & 15);
            if (mm < MMAX) {
                int vv = comp * 2 + (r >> 4);
                uint2 val = *(const uint2*)&st[cur][r][ch * 4];
                *(uint2*)(ao + (((size_t)vv * BC + bc) * MMAX + mm) * NLAT
                               + kq * 64 + ch * 4) = val;
            }
        }
    }
    #undef STAGE_F
}

// ---------------------------------------------------------------------------
// K2: contraction via MFMA (validated rounds 11-17, unchanged).
// ---------------------------------------------------------------------------
template <int MODE>
__global__ __launch_bounds__(512) void contract_mfma(const unsigned short* __restrict__ a,
                                                     const float* __restrict__ w,
                                                     void* __restrict__ outv)
{
    __shared__ __align__(16) unsigned char lds[25600];
    int m  = blockIdx.x;
    int lh = blockIdx.y;            // 0..3
    int t = threadIdx.x;
    int wid = t >> 6, lane = t & 63;
    int o = wid >> 2, h = (wid >> 1) & 1, q = wid & 1;
    int r15 = lane & 15, hi = lane >> 4;
    int l0 = lh * 64;

    f32x4 acc[4][2] = {};

    for (int kt2 = 0; kt2 < 16; ++kt2) {
        int phase = kt2 >> 3;
        int k0 = (kt2 & 7) * 32;
        __syncthreads();
        #pragma unroll
        for (int i = 0; i < 2; ++i) {
            int e = t + i * 512;
            int pl  = e >> 9;
            int bcr = (e >> 2) & 127;
            int ch  = e & 3;
            int vsel = (pl == 0) ? (phase ? 3 : 0) : (phase ? 1 : 2);
            size_t gidx = (((size_t)vsel * BC + bcr) * MMAX + m) * NLAT + k0 + ch * 8;
            uint4 val = *(const uint4*)(a + gidx);
            if (pl == 0 && phase) {
                val.x ^= 0x80008000u; val.y ^= 0x80008000u;
                val.z ^= 0x80008000u; val.w ^= 0x80008000u;
            }
            *(uint4*)(lds + ((size_t)(pl * 128 + bcr)) * 80 + ch * 16) = val;
        }
        {
            int l = t >> 3, ch = t & 7;
            size_t gw = (((size_t)phase * MMAX + m) * LMAX + l0 + l) * NLAT + k0 + ch * 4;
            float4 f0 = *(const float4*)(w + gw);
            uint2 vv = make_uint2(bfpack2(f0.x, f0.y), bfpack2(f0.z, f0.w));
            *(uint2*)(lds + 20480 + (size_t)l * 80 + ch * 8) = vv;
        }
        __syncthreads();

        bf16x8 bfr0 = *(const bf16x8*)(lds + 20480 + (size_t)(q * 32 + r15) * 80 + hi * 16);
        bf16x8 bfr1 = *(const bf16x8*)(lds + 20480 + (size_t)(q * 32 + 16 + r15) * 80 + hi * 16);
        #pragma unroll
        for (int bt = 0; bt < 4; ++bt) {
            bf16x8 af = *(const bf16x8*)(lds + (size_t)(o * 128 + h * 64 + bt * 16 + r15) * 80 + hi * 16);
            acc[bt][0] = __builtin_amdgcn_mfma_f32_16x16x32_bf16(af, bfr0, acc[bt][0], 0, 0, 0);
            acc[bt][1] = __builtin_amdgcn_mfma_f32_16x16x32_bf16(af, bfr1, acc[bt][1], 0, 0, 0);
        }
    }

    float sgn = (o == 1) ? -1.0f : 1.0f;
    #pragma unroll
    for (int bt = 0; bt < 4; ++bt) {
        #pragma unroll
        for (int lt = 0; lt < 2; ++lt) {
            #pragma unroll
            for (int j = 0; j < 4; ++j) {
                int bc = h * 64 + bt * 16 + hi * 4 + j;
                int l  = l0 + q * 32 + lt * 16 + r15;
                float val = sgn * acc[bt][lt][j];
                if (MODE == 0) {
                    __hip_bfloat16* outs = (__hip_bfloat16*)outv;
                    outs[(((size_t)m * 2 + o) * BC + bc) * LMAX + l] = __float2bfloat16(val);
                } else {
                    float* out = (float*)outv;
                    out[(((size_t)bc * 2 + o) * LMAX + l) * MMAX + m] = val;
                }
            }
        }
    }
}

// ---------------------------------------------------------------------------
// K3: transpose outs[m][o][bc][l] bf16 -> out[bc][o][l][m] fp32 (validated).
// ---------------------------------------------------------------------------
__global__ __launch_bounds__(256) void transpose_out(const unsigned short* __restrict__ outs,
                                                     float* __restrict__ out)
{
    __shared__ float tile[32][65];
    int mt = blockIdx.x;            // 0..8
    int lt = blockIdx.y;            // 0..3
    int z  = blockIdx.z;            // 0..255
    int bc = z >> 1, o = z & 1;
    int t = threadIdx.x;

    {
        int r = t >> 3, c0 = (t & 7) * 8;
        int mm = mt * 32 + r;
        if (mm < MMAX) {
            const unsigned short* src = outs + (((size_t)mm * 2 + o) * BC + bc) * LMAX + lt * 64 + c0;
            uint4 v = *(const uint4*)src;
            const unsigned short* u = (const unsigned short*)&v;
            #pragma unroll
            for (int i = 0; i < 8; ++i)
                tile[r][c0 + i] = __bfloat162float(__builtin_bit_cast(__hip_bfloat16, u[i]));
        }
    }
    __syncthreads();
    {
        int l = t >> 2, mc = (t & 3) * 8;
        float* dst = out + (((size_t)bc * 2 + o) * LMAX + lt * 64 + l) * MMAX + mt * 32 + mc;
        #pragma unroll
        for (int i = 0; i < 8; ++i) {
            int mm = mt * 32 + mc + i;
            if (mm < MMAX) dst[i] = tile[mc + i][l];
        }
    }
}

// ---------------------------------------------------------------------------
// Legacy proven path (round 9) — fallback for small ws.
// ---------------------------------------------------------------------------
#define PER_BC ((size_t)4 * MMAX * NLAT * sizeof(__hip_bfloat16))

__global__ __launch_bounds__(256) void dft_legacy(const float* __restrict__ x,
                                                  __hip_bfloat16* __restrict__ a,
                                                  int bc0, int nbc)
{
    __shared__ float  xs[512];
    __shared__ float2 tw[512];
    int t = threadIdx.x;
    int b = blockIdx.x;
    int lat = b & (NLAT - 1);
    int comp = (b >> 8) & 1;
    int bcl = b >> 9;
    int bc = bc0 + bcl;
    const float* xr = x + (((size_t)bc * 2 + comp) * NLAT + lat) * NLON;
    for (int j = t; j < 512; j += 256) {
        xs[j] = xr[j];
        float ang = -6.283185307179586f * (float)j / 512.0f;
        float sn, cs; sincosf(ang, &sn, &cs);
        tw[j] = make_float2(cs, sn);
    }
    __syncthreads();
    const float scale = 6.283185307179586f / 512.0f;
    size_t VS = (size_t)nbc * MMAX * NLAT;
    __hip_bfloat16* p0 = a + (size_t)(comp * 2) * VS + (size_t)bcl * MMAX * NLAT + lat;
    __hip_bfloat16* p1 = p0 + VS;
    for (int m = t; m < MMAX; m += 256) {
        float accr = 0.f, acci = 0.f;
        int j = 0;
        for (int n = 0; n < 512; ++n) {
            float xv = xs[n]; float2 wv = tw[j];
            accr += xv * wv.x; acci += xv * wv.y;
            j = (j + m) & 511;
        }
        p0[(size_t)m * NLAT] = __float2bfloat16(accr * scale);
        p1[(size_t)m * NLAT] = __float2bfloat16(acci * scale);
    }
}

__global__ __launch_bounds__(256) void contract_legacy(const __hip_bfloat16* __restrict__ a,
                                                       const float* __restrict__ w,
                                                       float* __restrict__ out,
                                                       int bc0, int nbc)
{
    __shared__ float w0s[16][NLAT + 1];
    __shared__ float w1s[16][NLAT + 1];
    __shared__ float as[4][4][NLAT + 1];
    __shared__ float2 red2[256];
    int tid = threadIdx.x;
    int m = blockIdx.x, l0 = blockIdx.y * 16, bct = blockIdx.z * 4;
    const float* w0g = w + ((size_t)m * LMAX + l0) * NLAT;
    const float* w1g = w0g + (size_t)MMAX * LMAX * NLAT;
    for (int idx = tid; idx < 16 * NLAT; idx += 256) {
        int l = idx >> 8, k = idx & 255;
        w0s[l][k] = w0g[(size_t)l * NLAT + k];
        w1s[l][k] = w1g[(size_t)l * NLAT + k];
    }
    size_t VS = (size_t)nbc * MMAX * NLAT;
    for (int idx = tid; idx < 4 * 4 * NLAT; idx += 256) {
        int v = idx >> 10, bl = (idx >> 8) & 3, k = idx & 255;
        int bls = bct + bl; if (bls > nbc - 1) bls = nbc - 1;
        as[v][bl][k] = __bfloat162float(a[(size_t)v * VS + ((size_t)bls * MMAX + m) * NLAT + k]);
    }
    __syncthreads();
    int l = tid & 15, b = (tid >> 4) & 3, kseg = tid >> 6;
    float acc0 = 0.f, acc2 = 0.f;
    int kbeg = kseg * 64;
    #pragma unroll 8
    for (int k = kbeg; k < kbeg + 64; ++k) {
        float tr = as[0][b][k], ti = as[1][b][k], pr = as[2][b][k], pi = as[3][b][k];
        float w0 = w0s[l][k], w1 = w1s[l][k];
        acc0 += tr * w0 - pi * w1;
        acc2 -= ti * w1 + pr * w0;
    }
    red2[tid] = make_float2(acc0, acc2);
    __syncthreads();
    if (kseg == 0 && (bct + b) < nbc) {
        #pragma unroll
        for (int s = 1; s < 4; ++s) {
            float2 r = red2[tid + 64 * s];
            acc0 += r.x; acc2 += r.y;
        }
        int bc = bc0 + bct + b;
        out[(((size_t)bc * 2 + 0) * LMAX + (l0 + l)) * MMAX + m] = acc0;
        out[(((size_t)bc * 2 + 1) * LMAX + (l0 + l)) * MMAX + m] = acc2;
    }
}

extern "C" void kernel_launch(void* const* d_in, const int* in_sizes, int n_in,
                              void* d_out, int out_size, void* d_ws, size_t ws_size,
                              hipStream_t stream)
{
    const float* x = (const float*)d_in[0];
    const float* w = (const float*)d_in[1];
    if (n_in >= 2) {
        long long s0 = (long long)in_sizes[0];
        if (s0 == (long long)W_ELEMS || s0 == W_BYTES) {
            w = (const float*)d_in[0];
            x = (const float*)d_in[1];
        }
    }
    float* out = (float*)d_out;

    if (ws_size >= F_BYTES + A_BYTES) {
        unsigned short* F = (unsigned short*)d_ws;
        unsigned short* a = (unsigned short*)((char*)d_ws + F_BYTES);
        hipLaunchKernelGGL(f_init, dim3(FM, 2), dim3(256), 0, stream, F);
        hipLaunchKernelGGL(dft_mfma, dim3(256, 4), dim3(512), 0, stream, x, F, a);
        if (ws_size >= F_BYTES + A_BYTES + OUTS_BYTES) {
            unsigned short* outs = (unsigned short*)((char*)d_ws + F_BYTES + A_BYTES);
            hipLaunchKernelGGL((contract_mfma<0>), dim3(MMAX, 4), dim3(512), 0, stream,
                               a, w, (void*)outs);
            hipLaunchKernelGGL(transpose_out, dim3(9, 4, 256), dim3(256), 0, stream,
                               outs, out);
        } else {
            hipLaunchKernelGGL((contract_mfma<1>), dim3(MMAX, 4), dim3(512), 0, stream,
                               a, w, (void*)out);
        }
    } else {
        __hip_bfloat16* a = (__hip_bfloat16*)d_ws;
        int nbc = 1;
        for (int c = 128; c >= 1; c >>= 1)
            if (PER_BC * (size_t)c <= ws_size) { nbc = c; break; }
        int nchunks = BC / nbc;
        for (int cc = 0; cc < nchunks; ++cc) {
            int bc0 = cc * nbc;
            hipLaunchKernelGGL(dft_legacy, dim3(nbc * 2 * NLAT), dim3(256), 0, stream,
                               x, a, bc0, nbc);
            hipLaunchKernelGGL(contract_legacy, dim3(MMAX, LMAX / 16, (nbc + 3) / 4),
                               dim3(256), 0, stream, a, w, out, bc0, nbc);
        }
    }
}

// Round 19
// 242.733 us; speedup vs baseline: 1.0587x; 1.0587x over previous
//
#include <hip/hip_runtime.h>
#include <hip/hip_bf16.h>
#include <math.h>

#define NLAT 256
#define NLON 512
#define LMAX 256
#define MMAX 257
#define BC   128

#define X_ELEMS 33554432
#define W_ELEMS 33685504
#define W_BYTES (W_ELEMS * 4LL)

#define FM    288                      // padded m rows for F
#define F_BYTES  ((size_t)2*FM*512*2)                    // 589,824
#define A_BYTES  ((size_t)4*BC*MMAX*NLAT*2)              // 67,371,008
#define OUTS_BYTES ((size_t)MMAX*2*BC*LMAX*2)            // 33,685,504

typedef short bf16x8 __attribute__((ext_vector_type(8)));
typedef float f32x4  __attribute__((ext_vector_type(4)));

__device__ __forceinline__ unsigned int bfpack2(float a, float b) {
    unsigned short lo = __builtin_bit_cast(unsigned short, __float2bfloat16(a));
    unsigned short hi = __builtin_bit_cast(unsigned short, __float2bfloat16(b));
    return (unsigned int)lo | ((unsigned int)hi << 16);
}
__device__ __forceinline__ unsigned short bf16bits(float a) {
    return __builtin_bit_cast(unsigned short, __float2bfloat16(a));
}
__device__ __forceinline__ void gload16(const void* g, void* l) {
    __builtin_amdgcn_global_load_lds(
        (const __attribute__((address_space(1))) unsigned int*)g,
        (__attribute__((address_space(3))) unsigned int*)l, 16, 0, 0);
}

// ---------------------------------------------------------------------------
// K0: build DFT matrix F[o][mm][n] bf16, scale 2*pi/512 folded in.
// ---------------------------------------------------------------------------
__global__ __launch_bounds__(256) void f_init(unsigned short* __restrict__ F)
{
    int mm = blockIdx.x, o = blockIdx.y, t = threadIdx.x;
    const float s = 6.283185307179586f / 512.0f;
    for (int c = 0; c < 2; ++c) {
        int n = t * 2 + c;
        float val = 0.0f;
        if (mm < MMAX) {
            int j = (mm * n) & 511;
            float ang = 6.283185307179586f * (float)j / 512.0f;
            float sn, cs; __sincosf(ang, &sn, &cs);
            val = (o == 0) ? s * cs : -s * sn;
        }
        F[((size_t)o * FM + mm) * 512 + n] =
            __builtin_bit_cast(unsigned short, __float2bfloat16(val));
    }
}

// ---------------------------------------------------------------------------
// K1 v8: DFT via MFMA (validated r18; unchanged).
// ---------------------------------------------------------------------------
__global__ __launch_bounds__(512, 1) void dft_mfma(const float* __restrict__ x,
                                                   const unsigned short* __restrict__ F,
                                                   unsigned short* __restrict__ aout)
{
    __shared__ __align__(16) unsigned char smem[65536];      // xl THEN fl[2][32768]
    __shared__ __align__(16) unsigned short st[2][32][72];   // D tile [2o x 16m][64k]
    unsigned char* xl = smem;
    unsigned char (*fl)[32768] = (unsigned char (*)[32768])smem;

    int bcc = blockIdx.x;           // 0..255
    int kq  = blockIdx.y;           // 0..3
    int bc = bcc >> 1, comp = bcc & 1;
    int t = threadIdx.x;
    int wid = t >> 6, lane = t & 63;

    {
        const float* xg = x + ((size_t)bcc * NLAT + kq * 64) * NLON;
        #pragma unroll
        for (int p = 0; p < 8; ++p) {
            int row = wid * 8 + p;
            const float* src = xg + (size_t)row * NLON + lane * 8;
            float4 f0 = *(const float4*)(src);
            float4 f1 = *(const float4*)(src + 4);
            uint4 v;
            v.x = bfpack2(f0.x, f0.y); v.y = bfpack2(f0.z, f0.w);
            v.z = bfpack2(f1.x, f1.y); v.w = bfpack2(f1.z, f1.w);
            unsigned off = ((unsigned)row * 1024u + (unsigned)lane * 16u)
                           ^ ((unsigned)(row & 15) << 4);
            *(uint4*)(xl + off) = v;
        }
    }
    __syncthreads();

    int o = wid >> 2, kt = wid & 3;
    int r15 = lane & 15, hi = lane >> 4;
    int klocal = kt * 16 + r15;
    unsigned braw = (unsigned)klocal * 1024u;
    unsigned bswz = (unsigned)(klocal & 15) << 4;

    bf16x8 barr[16];
    #pragma unroll
    for (int nt = 0; nt < 16; ++nt) {
        unsigned c0 = (unsigned)(nt * 64 + hi * 16);
        barr[nt] = *(const bf16x8*)(xl + ((braw + c0) ^ bswz));
    }
    __syncthreads();

    const unsigned char* Fb = (const unsigned char*)F;
    unsigned gcol = ((unsigned)lane * 16u);

    #define STAGE_F(buf, mt)                                                  \
        {                                                                     \
            _Pragma("unroll")                                                 \
            for (int p = 0; p < 4; ++p) {                                     \
                int fr = wid * 4 + p;                                         \
                int o2 = fr >> 4, mr = fr & 15;                               \
                size_t grow = (size_t)o2 * FM + (mt) * 16 + mr;               \
                const void* g = Fb + grow * 1024u                             \
                                + (gcol ^ ((unsigned)(fr & 15) << 4));        \
                gload16(g, (unsigned char*)fl[buf] + (unsigned)fr * 1024u);   \
            }                                                                 \
        }

    STAGE_F(0, 0);
    __syncthreads();

    unsigned arow = (unsigned)(o * 16 + r15);
    unsigned abase = arow * 1024u;
    unsigned aswz = (unsigned)r15 << 4;
    unsigned short* ao = aout;

    for (int mt = 0; mt < 17; ++mt) {
        int cur = mt & 1;
        if (mt < 16) STAGE_F(cur ^ 1, mt + 1);

        const unsigned char* fb = fl[cur];
        f32x4 acc0 = {0.f,0.f,0.f,0.f}, acc1 = {0.f,0.f,0.f,0.f};
        f32x4 acc2 = {0.f,0.f,0.f,0.f}, acc3 = {0.f,0.f,0.f,0.f};
        #pragma unroll
        for (int nt = 0; nt < 16; nt += 4) {
            unsigned c0 = (unsigned)(nt * 64 + hi * 16);
            bf16x8 a0 = *(const bf16x8*)(fb + ((abase + c0)        ^ aswz));
            bf16x8 a1 = *(const bf16x8*)(fb + ((abase + c0 + 64u)  ^ aswz));
            bf16x8 a2 = *(const bf16x8*)(fb + ((abase + c0 + 128u) ^ aswz));
            bf16x8 a3 = *(const bf16x8*)(fb + ((abase + c0 + 192u) ^ aswz));
            acc0 = __builtin_amdgcn_mfma_f32_16x16x32_bf16(a0, barr[nt],     acc0, 0, 0, 0);
            acc1 = __builtin_amdgcn_mfma_f32_16x16x32_bf16(a1, barr[nt + 1], acc1, 0, 0, 0);
            acc2 = __builtin_amdgcn_mfma_f32_16x16x32_bf16(a2, barr[nt + 2], acc2, 0, 0, 0);
            acc3 = __builtin_amdgcn_mfma_f32_16x16x32_bf16(a3, barr[nt + 3], acc3, 0, 0, 0);
        }
        #pragma unroll
        for (int j = 0; j < 4; ++j)
            acc0[j] = (acc0[j] + acc1[j]) + (acc2[j] + acc3[j]);

        {
            int rbase = o * 16 + hi * 4;
            #pragma unroll
            for (int j = 0; j < 4; ++j)
                st[cur][rbase + j][klocal] = bf16bits(acc0[j]);
        }
        __syncthreads();

        {
            int r = t >> 4, ch = t & 15;
            int mm = mt * 16 + (r & 15);
            if (mm < MMAX) {
                int vv = comp * 2 + (r >> 4);
                uint2 val = *(const uint2*)&st[cur][r][ch * 4];
                *(uint2*)(ao + (((size_t)vv * BC + bc) * MMAX + mm) * NLAT
                               + kq * 64 + ch * 4) = val;
            }
        }
    }
    #undef STAGE_F
}

// ---------------------------------------------------------------------------
// K2 v2: contraction via MFMA, double-buffered staging, 1 barrier/iter.
// A staged RAW via global_load_lds (linear dest: byte off = e*16);
// w via reg-path (issue-early / ds_write-late, T14). Phase-split accs:
//   accLo (kt2 0-7, w0): o=0 Σtr·w0, o=1 Σpr·w0
//   accHi (kt2 8-15, w1): o=0 Σpi·w1, o=1 Σti·w1
//   out0 = accLo - accHi ; out1 = -(accLo + accHi)
// grid (m:257, lh:4), 512 thr = 8 waves (o:2, h:2, q:2).
// ---------------------------------------------------------------------------
template <int MODE>
__global__ __launch_bounds__(512, 1) void contract_mfma(const unsigned short* __restrict__ a,
                                                        const float* __restrict__ w,
                                                        void* __restrict__ outv)
{
    __shared__ __align__(16) unsigned char Ab[2][16384];   // [pl*128+bcr][32k] bf16, 64B rows
    __shared__ __align__(16) unsigned char Bb[2][4096];    // [64 l][32 k] bf16, 64B rows
    int m  = blockIdx.x;
    int lh = blockIdx.y;            // 0..3
    int t = threadIdx.x;
    int wid = t >> 6, lane = t & 63;
    int o = wid >> 2, h = (wid >> 1) & 1, q = wid & 1;
    int r15 = lane & 15, hi = lane >> 4;
    int l0 = lh * 64;

    f32x4 accLo[4][2] = {};
    f32x4 accHi[4][2] = {};

    int bcr = t >> 2, ch4 = t & 3;          // A staging: 4 thr/row, 16B each
    int lB  = t >> 3, chB = t & 7;          // B staging: 8 thr/row, float4

    // A stage: chunk i=0 -> plane (phase? pi : tr), i=1 -> (phase? ti : pr)
    #define STAGE_A(buf, kt)                                                    \
        {                                                                       \
            int ph_ = (kt) >> 3;                                                \
            int k0_ = ((kt) & 7) * 32;                                          \
            _Pragma("unroll")                                                   \
            for (int i = 0; i < 2; ++i) {                                       \
                int vsel = (i == 0) ? (ph_ ? 3 : 0) : (ph_ ? 1 : 2);            \
                const void* g = a + (((size_t)vsel * BC + bcr) * MMAX + m) * NLAT \
                                  + k0_ + ch4 * 8;                              \
                gload16(g, Ab[buf] + wid * 1024 + i * 8192);                    \
            }                                                                   \
        }

    float4 wreg;
    #define WLOAD(kt)                                                           \
        {                                                                       \
            int ph_ = (kt) >> 3;                                                \
            int k0_ = ((kt) & 7) * 32;                                          \
            wreg = *(const float4*)(w + (((size_t)ph_ * MMAX + m) * LMAX + l0 + lB) * NLAT \
                                      + k0_ + chB * 4);                         \
        }
    #define BWRITE(buf)                                                         \
        {                                                                       \
            uint2 vv = make_uint2(bfpack2(wreg.x, wreg.y), bfpack2(wreg.z, wreg.w)); \
            *(uint2*)(Bb[buf] + lB * 64 + chB * 8) = vv;                        \
        }
    #define MFMA_PHASE(ACC)                                                     \
        {                                                                       \
            bf16x8 bfr0 = *(const bf16x8*)(bb + (q * 32 + r15) * 64 + hi * 16); \
            bf16x8 bfr1 = *(const bf16x8*)(bb + (q * 32 + 16 + r15) * 64 + hi * 16); \
            _Pragma("unroll")                                                   \
            for (int bt = 0; bt < 4; ++bt) {                                    \
                bf16x8 af = *(const bf16x8*)(ab + (o * 128 + h * 64 + bt * 16 + r15) * 64 + hi * 16); \
                ACC[bt][0] = __builtin_amdgcn_mfma_f32_16x16x32_bf16(af, bfr0, ACC[bt][0], 0, 0, 0); \
                ACC[bt][1] = __builtin_amdgcn_mfma_f32_16x16x32_bf16(af, bfr1, ACC[bt][1], 0, 0, 0); \
            }                                                                   \
        }

    // prologue: stage kt2=0 into buf0
    STAGE_A(0, 0);
    WLOAD(0);
    __syncthreads();            // drains A(0) gloads + wreg load
    BWRITE(0);

    for (int kt2 = 0; kt2 < 16; ++kt2) {
        int cur = kt2 & 1;
        if (kt2 < 15) WLOAD(kt2 + 1);          // private regs, pre-barrier OK
        __syncthreads();        // drains BWRITE(cur) [lgkm] + STAGE_A(cur) [vmcnt]
        if (kt2 < 15) STAGE_A(cur ^ 1, kt2 + 1);   // hidden under MFMA below

        const unsigned char* bb = Bb[cur];
        const unsigned char* ab = Ab[cur];
        if (kt2 < 8) MFMA_PHASE(accLo) else MFMA_PHASE(accHi);

        if (kt2 < 15) BWRITE(cur ^ 1);         // waits wreg vmcnt (hidden by MFMA)
    }

    #pragma unroll
    for (int bt = 0; bt < 4; ++bt) {
        #pragma unroll
        for (int lt = 0; lt < 2; ++lt) {
            #pragma unroll
            for (int j = 0; j < 4; ++j) {
                int bc = h * 64 + bt * 16 + hi * 4 + j;
                int l  = l0 + q * 32 + lt * 16 + r15;
                float lo = accLo[bt][lt][j];
                float hh = accHi[bt][lt][j];
                float val = (o == 0) ? (lo - hh) : (0.0f - (lo + hh));
                if (MODE == 0) {
                    __hip_bfloat16* outs = (__hip_bfloat16*)outv;
                    outs[(((size_t)m * 2 + o) * BC + bc) * LMAX + l] = __float2bfloat16(val);
                } else {
                    float* out = (float*)outv;
                    out[(((size_t)bc * 2 + o) * LMAX + l) * MMAX + m] = val;
                }
            }
        }
    }
    #undef STAGE_A
    #undef WLOAD
    #undef BWRITE
    #undef MFMA_PHASE
}

// ---------------------------------------------------------------------------
// K3: transpose outs[m][o][bc][l] bf16 -> out[bc][o][l][m] fp32 (validated).
// ---------------------------------------------------------------------------
__global__ __launch_bounds__(256) void transpose_out(const unsigned short* __restrict__ outs,
                                                     float* __restrict__ out)
{
    __shared__ float tile[32][65];
    int mt = blockIdx.x;            // 0..8
    int lt = blockIdx.y;            // 0..3
    int z  = blockIdx.z;            // 0..255
    int bc = z >> 1, o = z & 1;
    int t = threadIdx.x;

    {
        int r = t >> 3, c0 = (t & 7) * 8;
        int mm = mt * 32 + r;
        if (mm < MMAX) {
            const unsigned short* src = outs + (((size_t)mm * 2 + o) * BC + bc) * LMAX + lt * 64 + c0;
            uint4 v = *(const uint4*)src;
            const unsigned short* u = (const unsigned short*)&v;
            #pragma unroll
            for (int i = 0; i < 8; ++i)
                tile[r][c0 + i] = __bfloat162float(__builtin_bit_cast(__hip_bfloat16, u[i]));
        }
    }
    __syncthreads();
    {
        int l = t >> 2, mc = (t & 3) * 8;
        float* dst = out + (((size_t)bc * 2 + o) * LMAX + lt * 64 + l) * MMAX + mt * 32 + mc;
        #pragma unroll
        for (int i = 0; i < 8; ++i) {
            int mm = mt * 32 + mc + i;
            if (mm < MMAX) dst[i] = tile[mc + i][l];
        }
    }
}

// ---------------------------------------------------------------------------
// Legacy proven path (round 9) — fallback for small ws.
// ---------------------------------------------------------------------------
#define PER_BC ((size_t)4 * MMAX * NLAT * sizeof(__hip_bfloat16))

__global__ __launch_bounds__(256) void dft_legacy(const float* __restrict__ x,
                                                  __hip_bfloat16* __restrict__ a,
                                                  int bc0, int nbc)
{
    __shared__ float  xs[512];
    __shared__ float2 tw[512];
    int t = threadIdx.x;
    int b = blockIdx.x;
    int lat = b & (NLAT - 1);
    int comp = (b >> 8) & 1;
    int bcl = b >> 9;
    int bc = bc0 + bcl;
    const float* xr = x + (((size_t)bc * 2 + comp) * NLAT + lat) * NLON;
    for (int j = t; j < 512; j += 256) {
        xs[j] = xr[j];
        float ang = -6.283185307179586f * (float)j / 512.0f;
        float sn, cs; sincosf(ang, &sn, &cs);
        tw[j] = make_float2(cs, sn);
    }
    __syncthreads();
    const float scale = 6.283185307179586f / 512.0f;
    size_t VS = (size_t)nbc * MMAX * NLAT;
    __hip_bfloat16* p0 = a + (size_t)(comp * 2) * VS + (size_t)bcl * MMAX * NLAT + lat;
    __hip_bfloat16* p1 = p0 + VS;
    for (int m = t; m < MMAX; m += 256) {
        float accr = 0.f, acci = 0.f;
        int j = 0;
        for (int n = 0; n < 512; ++n) {
            float xv = xs[n]; float2 wv = tw[j];
            accr += xv * wv.x; acci += xv * wv.y;
            j = (j + m) & 511;
        }
        p0[(size_t)m * NLAT] = __float2bfloat16(accr * scale);
        p1[(size_t)m * NLAT] = __float2bfloat16(acci * scale);
    }
}

__global__ __launch_bounds__(256) void contract_legacy(const __hip_bfloat16* __restrict__ a,
                                                       const float* __restrict__ w,
                                                       float* __restrict__ out,
                                                       int bc0, int nbc)
{
    __shared__ float w0s[16][NLAT + 1];
    __shared__ float w1s[16][NLAT + 1];
    __shared__ float as[4][4][NLAT + 1];
    __shared__ float2 red2[256];
    int tid = threadIdx.x;
    int m = blockIdx.x, l0 = blockIdx.y * 16, bct = blockIdx.z * 4;
    const float* w0g = w + ((size_t)m * LMAX + l0) * NLAT;
    const float* w1g = w0g + (size_t)MMAX * LMAX * NLAT;
    for (int idx = tid; idx < 16 * NLAT; idx += 256) {
        int l = idx >> 8, k = idx & 255;
        w0s[l][k] = w0g[(size_t)l * NLAT + k];
        w1s[l][k] = w1g[(size_t)l * NLAT + k];
    }
    size_t VS = (size_t)nbc * MMAX * NLAT;
    for (int idx = tid; idx < 4 * 4 * NLAT; idx += 256) {
        int v = idx >> 10, bl = (idx >> 8) & 3, k = idx & 255;
        int bls = bct + bl; if (bls > nbc - 1) bls = nbc - 1;
        as[v][bl][k] = __bfloat162float(a[(size_t)v * VS + ((size_t)bls * MMAX + m) * NLAT + k]);
    }
    __syncthreads();
    int l = tid & 15, b = (tid >> 4) & 3, kseg = tid >> 6;
    float acc0 = 0.f, acc2 = 0.f;
    int kbeg = kseg * 64;
    #pragma unroll 8
    for (int k = kbeg; k < kbeg + 64; ++k) {
        float tr = as[0][b][k], ti = as[1][b][k], pr = as[2][b][k], pi = as[3][b][k];
        float w0 = w0s[l][k], w1 = w1s[l][k];
        acc0 += tr * w0 - pi * w1;
        acc2 -= ti * w1 + pr * w0;
    }
    red2[tid] = make_float2(acc0, acc2);
    __syncthreads();
    if (kseg == 0 && (bct + b) < nbc) {
        #pragma unroll
        for (int s = 1; s < 4; ++s) {
            float2 r = red2[tid + 64 * s];
            acc0 += r.x; acc2 += r.y;
        }
        int bc = bc0 + bct + b;
        out[(((size_t)bc * 2 + 0) * LMAX + (l0 + l)) * MMAX + m] = acc0;
        out[(((size_t)bc * 2 + 1) * LMAX + (l0 + l)) * MMAX + m] = acc2;
    }
}

extern "C" void kernel_launch(void* const* d_in, const int* in_sizes, int n_in,
                              void* d_out, int out_size, void* d_ws, size_t ws_size,
                              hipStream_t stream)
{
    const float* x = (const float*)d_in[0];
    const float* w = (const float*)d_in[1];
    if (n_in >= 2) {
        long long s0 = (long long)in_sizes[0];
        if (s0 == (long long)W_ELEMS || s0 == W_BYTES) {
            w = (const float*)d_in[0];
            x = (const float*)d_in[1];
        }
    }
    float* out = (float*)d_out;

    if (ws_size >= F_BYTES + A_BYTES) {
        unsigned short* F = (unsigned short*)d_ws;
        unsigned short* a = (unsigned short*)((char*)d_ws + F_BYTES);
        hipLaunchKernelGGL(f_init, dim3(FM, 2), dim3(256), 0, stream, F);
        hipLaunchKernelGGL(dft_mfma, dim3(256, 4), dim3(512), 0, stream, x, F, a);
        if (ws_size >= F_BYTES + A_BYTES + OUTS_BYTES) {
            unsigned short* outs = (unsigned short*)((char*)d_ws + F_BYTES + A_BYTES);
            hipLaunchKernelGGL((contract_mfma<0>), dim3(MMAX, 4), dim3(512), 0, stream,
                               a, w, (void*)outs);
            hipLaunchKernelGGL(transpose_out, dim3(9, 4, 256), dim3(256), 0, stream,
                               outs, out);
        } else {
            hipLaunchKernelGGL((contract_mfma<1>), dim3(MMAX, 4), dim3(512), 0, stream,
                               a, w, (void*)out);
        }
    } else {
        __hip_bfloat16* a = (__hip_bfloat16*)d_ws;
        int nbc = 1;
        for (int c = 128; c >= 1; c >>= 1)
            if (PER_BC * (size_t)c <= ws_size) { nbc = c; break; }
        int nchunks = BC / nbc;
        for (int cc = 0; cc < nchunks; ++cc) {
            int bc0 = cc * nbc;
            hipLaunchKernelGGL(dft_legacy, dim3(nbc * 2 * NLAT), dim3(256), 0, stream,
                               x, a, bc0, nbc);
            hipLaunchKernelGGL(contract_legacy, dim3(MMAX, LMAX / 16, (nbc + 3) / 4),
                               dim3(256), 0, stream, a, w, out, bc0, nbc);
        }
    }
}

// Round 20
// 216.172 us; speedup vs baseline: 1.1888x; 1.1229x over previous
//
#include <hip/hip_runtime.h>
#include <hip/hip_bf16.h>
#include <math.h>

#define NLAT 256
#define NLON 512
#define LMAX 256
#define MMAX 257
#define BC   128

#define X_ELEMS 33554432
#define W_ELEMS 33685504
#define W_BYTES (W_ELEMS * 4LL)

#define FM    288                      // padded m rows for F
#define F_BYTES  ((size_t)2*FM*512*2)                    // 589,824
#define A_BYTES  ((size_t)4*BC*MMAX*NLAT*2)              // 67,371,008
#define OUTS_BYTES ((size_t)MMAX*2*BC*LMAX*2)            // 33,685,504

typedef short bf16x8 __attribute__((ext_vector_type(8)));
typedef float f32x4  __attribute__((ext_vector_type(4)));

__device__ __forceinline__ unsigned int bfpack2(float a, float b) {
    unsigned short lo = __builtin_bit_cast(unsigned short, __float2bfloat16(a));
    unsigned short hi = __builtin_bit_cast(unsigned short, __float2bfloat16(b));
    return (unsigned int)lo | ((unsigned int)hi << 16);
}
__device__ __forceinline__ unsigned short bf16bits(float a) {
    return __builtin_bit_cast(unsigned short, __float2bfloat16(a));
}
__device__ __forceinline__ void gload16(const void* g, void* l) {
    __builtin_amdgcn_global_load_lds(
        (const __attribute__((address_space(1))) unsigned int*)g,
        (__attribute__((address_space(3))) unsigned int*)l, 16, 0, 0);
}

// ---------------------------------------------------------------------------
// K0: build DFT matrix F[o][mm][n] bf16, scale 2*pi/512 folded in.
// ---------------------------------------------------------------------------
__global__ __launch_bounds__(256) void f_init(unsigned short* __restrict__ F)
{
    int mm = blockIdx.x, o = blockIdx.y, t = threadIdx.x;
    const float s = 6.283185307179586f / 512.0f;
    for (int c = 0; c < 2; ++c) {
        int n = t * 2 + c;
        float val = 0.0f;
        if (mm < MMAX) {
            int j = (mm * n) & 511;
            float ang = 6.283185307179586f * (float)j / 512.0f;
            float sn, cs; __sincosf(ang, &sn, &cs);
            val = (o == 0) ? s * cs : -s * sn;
        }
        F[((size_t)o * FM + mm) * 512 + n] =
            __builtin_bit_cast(unsigned short, __float2bfloat16(val));
    }
}

// ---------------------------------------------------------------------------
// K1 v9: DFT via MFMA. Each wave owns 128 k (2 reg-resident B halves) ->
// 2 MFMA per F LDS-read (halves LDS-read traffic/CU). grid (bcc:256, kh:2).
// x staged in 2 passes through the 64KB overlay; F via global_load_lds dbuf;
// 128k-wide LDS-staged full-line stores.
// ---------------------------------------------------------------------------
__global__ __launch_bounds__(512, 1) void dft_mfma(const float* __restrict__ x,
                                                   const unsigned short* __restrict__ F,
                                                   unsigned short* __restrict__ aout)
{
    __shared__ __align__(16) unsigned char smem[65536];      // xl (pass) THEN fl[2][32768]
    __shared__ __align__(16) unsigned short st[2][32][136];  // D tile [2o x 16m][128k]
    unsigned char* xl = smem;
    unsigned char (*fl)[32768] = (unsigned char (*)[32768])smem;

    int bcc = blockIdx.x;           // 0..255
    int kh  = blockIdx.y;           // 0..1
    int bc = bcc >> 1, comp = bcc & 1;
    int t = threadIdx.x;
    int wid = t >> 6, lane = t & 63;

    int o = wid >> 2, kt = wid & 3;
    int r15 = lane & 15, hi = lane >> 4;
    int klocal = kt * 16 + r15;
    unsigned braw = (unsigned)klocal * 1024u;
    unsigned bswz = (unsigned)(klocal & 15) << 4;

    // ---- stage x + hoist B fragments, two 64-row passes through xl
    bf16x8 barr0[16], barr1[16];
    #pragma unroll
    for (int s = 0; s < 2; ++s) {
        const float* xg = x + ((size_t)bcc * NLAT + kh * 128 + s * 64) * NLON;
        #pragma unroll
        for (int p = 0; p < 8; ++p) {
            int row = wid * 8 + p;
            const float* src = xg + (size_t)row * NLON + lane * 8;
            float4 f0 = *(const float4*)(src);
            float4 f1 = *(const float4*)(src + 4);
            uint4 v;
            v.x = bfpack2(f0.x, f0.y); v.y = bfpack2(f0.z, f0.w);
            v.z = bfpack2(f1.x, f1.y); v.w = bfpack2(f1.z, f1.w);
            unsigned off = ((unsigned)row * 1024u + (unsigned)lane * 16u)
                           ^ ((unsigned)(row & 15) << 4);
            *(uint4*)(xl + off) = v;
        }
        __syncthreads();            // x pass staged
        #pragma unroll
        for (int nt = 0; nt < 16; ++nt) {
            unsigned c0 = (unsigned)(nt * 64 + hi * 16);
            bf16x8 v = *(const bf16x8*)(xl + ((braw + c0) ^ bswz));
            if (s == 0) barr0[nt] = v; else barr1[nt] = v;
        }
        __syncthreads();            // all waves done reading xl
    }

    const unsigned char* Fb = (const unsigned char*)F;
    unsigned gcol = ((unsigned)lane * 16u);

    #define STAGE_F(buf, mt)                                                  \
        {                                                                     \
            _Pragma("unroll")                                                 \
            for (int p = 0; p < 4; ++p) {                                     \
                int fr = wid * 4 + p;                                         \
                int o2 = fr >> 4, mr = fr & 15;                               \
                size_t grow = (size_t)o2 * FM + (mt) * 16 + mr;               \
                const void* g = Fb + grow * 1024u                             \
                                + (gcol ^ ((unsigned)(fr & 15) << 4));        \
                gload16(g, (unsigned char*)fl[buf] + (unsigned)fr * 1024u);   \
            }                                                                 \
        }

    STAGE_F(0, 0);
    __syncthreads();

    unsigned arow = (unsigned)(o * 16 + r15);
    unsigned abase = arow * 1024u;
    unsigned aswz = (unsigned)r15 << 4;
    unsigned short* ao = aout;

    for (int mt = 0; mt < 17; ++mt) {
        int cur = mt & 1;
        if (mt < 16) STAGE_F(cur ^ 1, mt + 1);

        const unsigned char* fb = fl[cur];
        f32x4 accA0 = {0.f,0.f,0.f,0.f}, accA1 = {0.f,0.f,0.f,0.f};
        f32x4 accB0 = {0.f,0.f,0.f,0.f}, accB1 = {0.f,0.f,0.f,0.f};
        #pragma unroll
        for (int nt = 0; nt < 16; nt += 2) {
            unsigned c0 = (unsigned)(nt * 64 + hi * 16);
            bf16x8 a0 = *(const bf16x8*)(fb + ((abase + c0)       ^ aswz));
            bf16x8 a1 = *(const bf16x8*)(fb + ((abase + c0 + 64u) ^ aswz));
            accA0 = __builtin_amdgcn_mfma_f32_16x16x32_bf16(a0, barr0[nt],     accA0, 0, 0, 0);
            accB0 = __builtin_amdgcn_mfma_f32_16x16x32_bf16(a0, barr1[nt],     accB0, 0, 0, 0);
            accA1 = __builtin_amdgcn_mfma_f32_16x16x32_bf16(a1, barr0[nt + 1], accA1, 0, 0, 0);
            accB1 = __builtin_amdgcn_mfma_f32_16x16x32_bf16(a1, barr1[nt + 1], accB1, 0, 0, 0);
        }
        #pragma unroll
        for (int j = 0; j < 4; ++j) {
            accA0[j] += accA1[j];
            accB0[j] += accB1[j];
        }

        // stage D to LDS (row = o*16 + mm_local, col = s*64 + klocal)
        {
            int rbase = o * 16 + hi * 4;
            #pragma unroll
            for (int j = 0; j < 4; ++j) {
                st[cur][rbase + j][klocal]      = bf16bits(accA0[j]);
                st[cur][rbase + j][klocal + 64] = bf16bits(accB0[j]);
            }
        }
        __syncthreads();            // drains gload_lds(mt+1) + st writes

        // cooperative full-line store: 16 thr x 16B per (o,mm) row (128 k)
        {
            int r = t >> 4, ch = t & 15;
            int mm = mt * 16 + (r & 15);
            if (mm < MMAX) {
                int vv = comp * 2 + (r >> 4);
                uint4 val = *(const uint4*)&st[cur][r][ch * 8];
                *(uint4*)(ao + (((size_t)vv * BC + bc) * MMAX + mm) * NLAT
                               + kh * 128 + ch * 8) = val;
            }
        }
    }
    #undef STAGE_F
}

// ---------------------------------------------------------------------------
// K2 v3: contraction via MFMA. l-tile 128 (lt=4): 8 LDS reads / 16 MFMA.
// Ab XOR pre-swizzled via global source (linear gload_lds dest, m173);
// Bb rows padded to 80B. Phase-split accs as r19 (verified).
// grid (m:257, lh:2), 512 thr = 8 waves (o:2, h:2, q:2).
// ---------------------------------------------------------------------------
template <int MODE>
__global__ __launch_bounds__(512, 1) void contract_mfma(const unsigned short* __restrict__ a,
                                                        const float* __restrict__ w,
                                                        void* __restrict__ outv)
{
    __shared__ __align__(16) unsigned char Ab[2][16384];   // [pl*128+bcr][32k] 64B rows, swz
    __shared__ __align__(16) unsigned char Bb[2][10240];   // [128 l][32 k] 80B rows
    int m  = blockIdx.x;
    int lh = blockIdx.y;            // 0..1
    int t = threadIdx.x;
    int wid = t >> 6, lane = t & 63;
    int o = wid >> 2, h = (wid >> 1) & 1, q = wid & 1;
    int r15 = lane & 15, hi = lane >> 4;
    int l0 = lh * 128;

    f32x4 accLo[4][4] = {};
    f32x4 accHi[4][4] = {};

    int bcr = t >> 2, ch4 = t & 3;          // A staging: 4 thr/row, 16B each
    int lB  = t >> 2, chB = t & 3;          // B staging: 4 thr/row, 16B each

    // A stage: plane i=0 -> (phase? pi : tr), i=1 -> (phase? ti : pr).
    // Global k-offset pre-swizzled: col' = col ^ ((bcr&3)<<4) bytes.
    #define STAGE_A(buf, kt)                                                    \
        {                                                                       \
            int ph_ = (kt) >> 3;                                                \
            int k0_ = ((kt) & 7) * 32;                                          \
            _Pragma("unroll")                                                   \
            for (int i = 0; i < 2; ++i) {                                       \
                int vsel = (i == 0) ? (ph_ ? 3 : 0) : (ph_ ? 1 : 2);            \
                const void* g = a + (((size_t)vsel * BC + bcr) * MMAX + m) * NLAT \
                                  + k0_ + (ch4 ^ (bcr & 3)) * 8;                \
                gload16(g, Ab[buf] + wid * 1024 + i * 8192);                    \
            }                                                                   \
        }

    float4 wreg0, wreg1;
    #define WLOAD(kt)                                                           \
        {                                                                       \
            int ph_ = (kt) >> 3;                                                \
            int k0_ = ((kt) & 7) * 32;                                          \
            const float* wp = w + (((size_t)ph_ * MMAX + m) * LMAX + l0 + lB) * NLAT \
                                + k0_ + chB * 8;                                \
            wreg0 = *(const float4*)(wp);                                       \
            wreg1 = *(const float4*)(wp + 4);                                   \
        }
    #define BWRITE(buf)                                                         \
        {                                                                       \
            uint4 vv;                                                           \
            vv.x = bfpack2(wreg0.x, wreg0.y); vv.y = bfpack2(wreg0.z, wreg0.w); \
            vv.z = bfpack2(wreg1.x, wreg1.y); vv.w = bfpack2(wreg1.z, wreg1.w); \
            *(uint4*)(Bb[buf] + lB * 80 + chB * 16) = vv;                       \
        }
    #define MFMA_PHASE(ACC)                                                     \
        {                                                                       \
            bf16x8 bfr[4];                                                      \
            _Pragma("unroll")                                                   \
            for (int lt = 0; lt < 4; ++lt)                                      \
                bfr[lt] = *(const bf16x8*)(bb + (q * 64 + lt * 16 + r15) * 80 + hi * 16); \
            _Pragma("unroll")                                                   \
            for (int bt = 0; bt < 4; ++bt) {                                    \
                bf16x8 af = *(const bf16x8*)(ab + (o * 128 + h * 64 + bt * 16 + r15) * 64 \
                                               + ((hi * 16) ^ ((r15 & 3) << 4))); \
                _Pragma("unroll")                                               \
                for (int lt = 0; lt < 4; ++lt)                                  \
                    ACC[bt][lt] = __builtin_amdgcn_mfma_f32_16x16x32_bf16(af, bfr[lt], ACC[bt][lt], 0, 0, 0); \
            }                                                                   \
        }

    // prologue: stage kt2=0 into buf0
    STAGE_A(0, 0);
    WLOAD(0);
    __syncthreads();            // drains A(0) gloads + wreg load
    BWRITE(0);

    for (int kt2 = 0; kt2 < 16; ++kt2) {
        int cur = kt2 & 1;
        if (kt2 < 15) WLOAD(kt2 + 1);          // private regs, pre-barrier OK
        __syncthreads();        // drains BWRITE(cur) [lgkm] + STAGE_A(cur) [vmcnt]
        if (kt2 < 15) STAGE_A(cur ^ 1, kt2 + 1);   // hidden under MFMA below

        const unsigned char* bb = Bb[cur];
        const unsigned char* ab = Ab[cur];
        if (kt2 < 8) MFMA_PHASE(accLo) else MFMA_PHASE(accHi);

        if (kt2 < 15) BWRITE(cur ^ 1);         // waits wreg vmcnt (hidden by MFMA)
    }

    #pragma unroll
    for (int bt = 0; bt < 4; ++bt) {
        #pragma unroll
        for (int lt = 0; lt < 4; ++lt) {
            #pragma unroll
            for (int j = 0; j < 4; ++j) {
                int bc = h * 64 + bt * 16 + hi * 4 + j;
                int l  = l0 + q * 64 + lt * 16 + r15;
                float lo = accLo[bt][lt][j];
                float hh = accHi[bt][lt][j];
                float val = (o == 0) ? (lo - hh) : (0.0f - (lo + hh));
                if (MODE == 0) {
                    __hip_bfloat16* outs = (__hip_bfloat16*)outv;
                    outs[(((size_t)m * 2 + o) * BC + bc) * LMAX + l] = __float2bfloat16(val);
                } else {
                    float* out = (float*)outv;
                    out[(((size_t)bc * 2 + o) * LMAX + l) * MMAX + m] = val;
                }
            }
        }
    }
    #undef STAGE_A
    #undef WLOAD
    #undef BWRITE
    #undef MFMA_PHASE
}

// ---------------------------------------------------------------------------
// K3: transpose outs[m][o][bc][l] bf16 -> out[bc][o][l][m] fp32 (validated).
// ---------------------------------------------------------------------------
__global__ __launch_bounds__(256) void transpose_out(const unsigned short* __restrict__ outs,
                                                     float* __restrict__ out)
{
    __shared__ float tile[32][65];
    int mt = blockIdx.x;            // 0..8
    int lt = blockIdx.y;            // 0..3
    int z  = blockIdx.z;            // 0..255
    int bc = z >> 1, o = z & 1;
    int t = threadIdx.x;

    {
        int r = t >> 3, c0 = (t & 7) * 8;
        int mm = mt * 32 + r;
        if (mm < MMAX) {
            const unsigned short* src = outs + (((size_t)mm * 2 + o) * BC + bc) * LMAX + lt * 64 + c0;
            uint4 v = *(const uint4*)src;
            const unsigned short* u = (const unsigned short*)&v;
            #pragma unroll
            for (int i = 0; i < 8; ++i)
                tile[r][c0 + i] = __bfloat162float(__builtin_bit_cast(__hip_bfloat16, u[i]));
        }
    }
    __syncthreads();
    {
        int l = t >> 2, mc = (t & 3) * 8;
        float* dst = out + (((size_t)bc * 2 + o) * LMAX + lt * 64 + l) * MMAX + mt * 32 + mc;
        #pragma unroll
        for (int i = 0; i < 8; ++i) {
            int mm = mt * 32 + mc + i;
            if (mm < MMAX) dst[i] = tile[mc + i][l];
        }
    }
}

// ---------------------------------------------------------------------------
// Legacy proven path (round 9) — fallback for small ws.
// ---------------------------------------------------------------------------
#define PER_BC ((size_t)4 * MMAX * NLAT * sizeof(__hip_bfloat16))

__global__ __launch_bounds__(256) void dft_legacy(const float* __restrict__ x,
                                                  __hip_bfloat16* __restrict__ a,
                                                  int bc0, int nbc)
{
    __shared__ float  xs[512];
    __shared__ float2 tw[512];
    int t = threadIdx.x;
    int b = blockIdx.x;
    int lat = b & (NLAT - 1);
    int comp = (b >> 8) & 1;
    int bcl = b >> 9;
    int bc = bc0 + bcl;
    const float* xr = x + (((size_t)bc * 2 + comp) * NLAT + lat) * NLON;
    for (int j = t; j < 512; j += 256) {
        xs[j] = xr[j];
        float ang = -6.283185307179586f * (float)j / 512.0f;
        float sn, cs; sincosf(ang, &sn, &cs);
        tw[j] = make_float2(cs, sn);
    }
    __syncthreads();
    const float scale = 6.283185307179586f / 512.0f;
    size_t VS = (size_t)nbc * MMAX * NLAT;
    __hip_bfloat16* p0 = a + (size_t)(comp * 2) * VS + (size_t)bcl * MMAX * NLAT + lat;
    __hip_bfloat16* p1 = p0 + VS;
    for (int m = t; m < MMAX; m += 256) {
        float accr = 0.f, acci = 0.f;
        int j = 0;
        for (int n = 0; n < 512; ++n) {
            float xv = xs[n]; float2 wv = tw[j];
            accr += xv * wv.x; acci += xv * wv.y;
            j = (j + m) & 511;
        }
        p0[(size_t)m * NLAT] = __float2bfloat16(accr * scale);
        p1[(size_t)m * NLAT] = __float2bfloat16(acci * scale);
    }
}

__global__ __launch_bounds__(256) void contract_legacy(const __hip_bfloat16* __restrict__ a,
                                                       const float* __restrict__ w,
                                                       float* __restrict__ out,
                                                       int bc0, int nbc)
{
    __shared__ float w0s[16][NLAT + 1];
    __shared__ float w1s[16][NLAT + 1];
    __shared__ float as[4][4][NLAT + 1];
    __shared__ float2 red2[256];
    int tid = threadIdx.x;
    int m = blockIdx.x, l0 = blockIdx.y * 16, bct = blockIdx.z * 4;
    const float* w0g = w + ((size_t)m * LMAX + l0) * NLAT;
    const float* w1g = w0g + (size_t)MMAX * LMAX * NLAT;
    for (int idx = tid; idx < 16 * NLAT; idx += 256) {
        int l = idx >> 8, k = idx & 255;
        w0s[l][k] = w0g[(size_t)l * NLAT + k];
        w1s[l][k] = w1g[(size_t)l * NLAT + k];
    }
    size_t VS = (size_t)nbc * MMAX * NLAT;
    for (int idx = tid; idx < 4 * 4 * NLAT; idx += 256) {
        int v = idx >> 10, bl = (idx >> 8) & 3, k = idx & 255;
        int bls = bct + bl; if (bls > nbc - 1) bls = nbc - 1;
        as[v][bl][k] = __bfloat162float(a[(size_t)v * VS + ((size_t)bls * MMAX + m) * NLAT + k]);
    }
    __syncthreads();
    int l = tid & 15, b = (tid >> 4) & 3, kseg = tid >> 6;
    float acc0 = 0.f, acc2 = 0.f;
    int kbeg = kseg * 64;
    #pragma unroll 8
    for (int k = kbeg; k < kbeg + 64; ++k) {
        float tr = as[0][b][k], ti = as[1][b][k], pr = as[2][b][k], pi = as[3][b][k];
        float w0 = w0s[l][k], w1 = w1s[l][k];
        acc0 += tr * w0 - pi * w1;
        acc2 -= ti * w1 + pr * w0;
    }
    red2[tid] = make_float2(acc0, acc2);
    __syncthreads();
    if (kseg == 0 && (bct + b) < nbc) {
        #pragma unroll
        for (int s = 1; s < 4; ++s) {
            float2 r = red2[tid + 64 * s];
            acc0 += r.x; acc2 += r.y;
        }
        int bc = bc0 + bct + b;
        out[(((size_t)bc * 2 + 0) * LMAX + (l0 + l)) * MMAX + m] = acc0;
        out[(((size_t)bc * 2 + 1) * LMAX + (l0 + l)) * MMAX + m] = acc2;
    }
}

extern "C" void kernel_launch(void* const* d_in, const int* in_sizes, int n_in,
                              void* d_out, int out_size, void* d_ws, size_t ws_size,
                              hipStream_t stream)
{
    const float* x = (const float*)d_in[0];
    const float* w = (const float*)d_in[1];
    if (n_in >= 2) {
        long long s0 = (long long)in_sizes[0];
        if (s0 == (long long)W_ELEMS || s0 == W_BYTES) {
            w = (const float*)d_in[0];
            x = (const float*)d_in[1];
        }
    }
    float* out = (float*)d_out;

    if (ws_size >= F_BYTES + A_BYTES) {
        unsigned short* F = (unsigned short*)d_ws;
        unsigned short* a = (unsigned short*)((char*)d_ws + F_BYTES);
        hipLaunchKernelGGL(f_init, dim3(FM, 2), dim3(256), 0, stream, F);
        hipLaunchKernelGGL(dft_mfma, dim3(256, 2), dim3(512), 0, stream, x, F, a);
        if (ws_size >= F_BYTES + A_BYTES + OUTS_BYTES) {
            unsigned short* outs = (unsigned short*)((char*)d_ws + F_BYTES + A_BYTES);
            hipLaunchKernelGGL((contract_mfma<0>), dim3(MMAX, 2), dim3(512), 0, stream,
                               a, w, (void*)outs);
            hipLaunchKernelGGL(transpose_out, dim3(9, 4, 256), dim3(256), 0, stream,
                               outs, out);
        } else {
            hipLaunchKernelGGL((contract_mfma<1>), dim3(MMAX, 2), dim3(512), 0, stream,
                               a, w, (void*)out);
        }
    } else {
        __hip_bfloat16* a = (__hip_bfloat16*)d_ws;
        int nbc = 1;
        for (int c = 128; c >= 1; c >>= 1)
            if (PER_BC * (size_t)c <= ws_size) { nbc = c; break; }
        int nchunks = BC / nbc;
        for (int cc = 0; cc < nchunks; ++cc) {
            int bc0 = cc * nbc;
            hipLaunchKernelGGL(dft_legacy, dim3(nbc * 2 * NLAT), dim3(256), 0, stream,
                               x, a, bc0, nbc);
            hipLaunchKernelGGL(contract_legacy, dim3(MMAX, LMAX / 16, (nbc + 3) / 4),
                               dim3(256), 0, stream, a, w, out, bc0, nbc);
        }
    }
}

// Round 21
// 206.371 us; speedup vs baseline: 1.2453x; 1.0475x over previous
//
#include <hip/hip_runtime.h>
#include <hip/hip_bf16.h>
#include <math.h>

#define NLAT 256
#define NLON 512
#define LMAX 256
#define MMAX 257
#define BC   128

#define X_ELEMS 33554432
#define W_ELEMS 33685504
#define W_BYTES (W_ELEMS * 4LL)

#define FM    288                      // padded m rows for F
#define F_BYTES  ((size_t)2*FM*512*2)                    // 589,824
#define A_BYTES  ((size_t)4*BC*MMAX*NLAT*2)              // 67,371,008
#define OUTS_BYTES ((size_t)MMAX*2*BC*LMAX*2)            // 33,685,504

typedef short bf16x8 __attribute__((ext_vector_type(8)));
typedef float f32x4  __attribute__((ext_vector_type(4)));

__device__ __forceinline__ unsigned int bfpack2(float a, float b) {
    unsigned short lo = __builtin_bit_cast(unsigned short, __float2bfloat16(a));
    unsigned short hi = __builtin_bit_cast(unsigned short, __float2bfloat16(b));
    return (unsigned int)lo | ((unsigned int)hi << 16);
}
__device__ __forceinline__ unsigned short bf16bits(float a) {
    return __builtin_bit_cast(unsigned short, __float2bfloat16(a));
}
__device__ __forceinline__ void gload16(const void* g, void* l) {
    __builtin_amdgcn_global_load_lds(
        (const __attribute__((address_space(1))) unsigned int*)g,
        (__attribute__((address_space(3))) unsigned int*)l, 16, 0, 0);
}

// ---------------------------------------------------------------------------
// K0: build DFT matrix F[o][mm][n] bf16, scale 2*pi/512 folded in.
// ---------------------------------------------------------------------------
__global__ __launch_bounds__(256) void f_init(unsigned short* __restrict__ F)
{
    int mm = blockIdx.x, o = blockIdx.y, t = threadIdx.x;
    const float s = 6.283185307179586f / 512.0f;
    for (int c = 0; c < 2; ++c) {
        int n = t * 2 + c;
        float val = 0.0f;
        if (mm < MMAX) {
            int j = (mm * n) & 511;
            float ang = 6.283185307179586f * (float)j / 512.0f;
            float sn, cs; __sincosf(ang, &sn, &cs);
            val = (o == 0) ? s * cs : -s * sn;
        }
        F[((size_t)o * FM + mm) * 512 + n] =
            __builtin_bit_cast(unsigned short, __float2bfloat16(val));
    }
}

// ---------------------------------------------------------------------------
// K1 v10: DFT via MFMA. v9 + st-tile removed (direct 2B bf16 stores; r12
// proved line-merge keeps WRITE_SIZE flat) + 1 barrier/mt + LDS = exactly
// 64KB (fl dbuf, xl overlays it in the prologue) -> 2 blocks/CU candidate.
// grid (bcc:256, kh:2), 512 thr = 8 waves (o:2, kt:4).
// ---------------------------------------------------------------------------
__global__ __launch_bounds__(512, 1) void dft_mfma(const float* __restrict__ x,
                                                   const unsigned short* __restrict__ F,
                                                   unsigned short* __restrict__ aout)
{
    __shared__ __align__(16) unsigned char fl[2][32768];   // 64KB; prologue uses as xl
    unsigned char* xl = (unsigned char*)fl;

    int bcc = blockIdx.x;           // 0..255
    int kh  = blockIdx.y;           // 0..1
    int bc = bcc >> 1, comp = bcc & 1;
    int t = threadIdx.x;
    int wid = t >> 6, lane = t & 63;

    int o = wid >> 2, kt = wid & 3;
    int r15 = lane & 15, hi = lane >> 4;
    int klocal = kt * 16 + r15;
    unsigned braw = (unsigned)klocal * 1024u;
    unsigned bswz = (unsigned)(klocal & 15) << 4;

    // ---- stage x + hoist B fragments, two 64-row passes through xl (64KB)
    bf16x8 barr0[16], barr1[16];
    #pragma unroll
    for (int s = 0; s < 2; ++s) {
        const float* xg = x + ((size_t)bcc * NLAT + kh * 128 + s * 64) * NLON;
        #pragma unroll
        for (int p = 0; p < 8; ++p) {
            int row = wid * 8 + p;
            const float* src = xg + (size_t)row * NLON + lane * 8;
            float4 f0 = *(const float4*)(src);
            float4 f1 = *(const float4*)(src + 4);
            uint4 v;
            v.x = bfpack2(f0.x, f0.y); v.y = bfpack2(f0.z, f0.w);
            v.z = bfpack2(f1.x, f1.y); v.w = bfpack2(f1.z, f1.w);
            unsigned off = ((unsigned)row * 1024u + (unsigned)lane * 16u)
                           ^ ((unsigned)(row & 15) << 4);
            *(uint4*)(xl + off) = v;
        }
        __syncthreads();            // x pass staged
        #pragma unroll
        for (int nt = 0; nt < 16; ++nt) {
            unsigned c0 = (unsigned)(nt * 64 + hi * 16);
            bf16x8 v = *(const bf16x8*)(xl + ((braw + c0) ^ bswz));
            if (s == 0) barr0[nt] = v; else barr1[nt] = v;
        }
        __syncthreads();            // all waves done reading xl
    }

    const unsigned char* Fb = (const unsigned char*)F;
    unsigned gcol = ((unsigned)lane * 16u);

    #define STAGE_F(buf, mt)                                                  \
        {                                                                     \
            _Pragma("unroll")                                                 \
            for (int p = 0; p < 4; ++p) {                                     \
                int fr = wid * 4 + p;                                         \
                int o2 = fr >> 4, mr = fr & 15;                               \
                size_t grow = (size_t)o2 * FM + (mt) * 16 + mr;               \
                const void* g = Fb + grow * 1024u                             \
                                + (gcol ^ ((unsigned)(fr & 15) << 4));        \
                gload16(g, (unsigned char*)fl[buf] + (unsigned)fr * 1024u);   \
            }                                                                 \
        }

    STAGE_F(0, 0);
    __syncthreads();                // fl[0] ready

    unsigned arow = (unsigned)(o * 16 + r15);
    unsigned abase = arow * 1024u;
    unsigned aswz = (unsigned)r15 << 4;
    unsigned short* ao = aout;
    int v = comp * 2 + o;

    for (int mt = 0; mt < 17; ++mt) {
        int cur = mt & 1;
        if (mt < 16) STAGE_F(cur ^ 1, mt + 1);   // async; drained by barrier below

        const unsigned char* fb = fl[cur];
        f32x4 accA0 = {0.f,0.f,0.f,0.f}, accA1 = {0.f,0.f,0.f,0.f};
        f32x4 accB0 = {0.f,0.f,0.f,0.f}, accB1 = {0.f,0.f,0.f,0.f};
        #pragma unroll
        for (int nt = 0; nt < 16; nt += 2) {
            unsigned c0 = (unsigned)(nt * 64 + hi * 16);
            bf16x8 a0 = *(const bf16x8*)(fb + ((abase + c0)       ^ aswz));
            bf16x8 a1 = *(const bf16x8*)(fb + ((abase + c0 + 64u) ^ aswz));
            accA0 = __builtin_amdgcn_mfma_f32_16x16x32_bf16(a0, barr0[nt],     accA0, 0, 0, 0);
            accB0 = __builtin_amdgcn_mfma_f32_16x16x32_bf16(a0, barr1[nt],     accB0, 0, 0, 0);
            accA1 = __builtin_amdgcn_mfma_f32_16x16x32_bf16(a1, barr0[nt + 1], accA1, 0, 0, 0);
            accB1 = __builtin_amdgcn_mfma_f32_16x16x32_bf16(a1, barr1[nt + 1], accB1, 0, 0, 0);
        }
        #pragma unroll
        for (int j = 0; j < 4; ++j) {
            accA0[j] += accA1[j];
            accB0[j] += accB1[j];
        }

        // direct bf16 stores (line-merged in L2; r12-verified WRITE flat)
        #pragma unroll
        for (int j = 0; j < 4; ++j) {
            int mm0 = mt * 16 + hi * 4 + j;
            if (mm0 < MMAX) {
                size_t base = (((size_t)v * BC + bc) * MMAX + mm0) * NLAT + kh * 128;
                ao[base + klocal]      = bf16bits(accA0[j]);
                ao[base + klocal + 64] = bf16bits(accB0[j]);
            }
        }
        __syncthreads();   // drains STAGE_F(cur^1) + stores; fl[cur] reads done
    }
    #undef STAGE_F
}

// ---------------------------------------------------------------------------
// K2 v3: contraction via MFMA (validated r20, unchanged).
// ---------------------------------------------------------------------------
template <int MODE>
__global__ __launch_bounds__(512, 1) void contract_mfma(const unsigned short* __restrict__ a,
                                                        const float* __restrict__ w,
                                                        void* __restrict__ outv)
{
    __shared__ __align__(16) unsigned char Ab[2][16384];   // [pl*128+bcr][32k] 64B rows, swz
    __shared__ __align__(16) unsigned char Bb[2][10240];   // [128 l][32 k] 80B rows
    int m  = blockIdx.x;
    int lh = blockIdx.y;            // 0..1
    int t = threadIdx.x;
    int wid = t >> 6, lane = t & 63;
    int o = wid >> 2, h = (wid >> 1) & 1, q = wid & 1;
    int r15 = lane & 15, hi = lane >> 4;
    int l0 = lh * 128;

    f32x4 accLo[4][4] = {};
    f32x4 accHi[4][4] = {};

    int bcr = t >> 2, ch4 = t & 3;
    int lB  = t >> 2, chB = t & 3;

    #define STAGE_A(buf, kt)                                                    \
        {                                                                       \
            int ph_ = (kt) >> 3;                                                \
            int k0_ = ((kt) & 7) * 32;                                          \
            _Pragma("unroll")                                                   \
            for (int i = 0; i < 2; ++i) {                                       \
                int vsel = (i == 0) ? (ph_ ? 3 : 0) : (ph_ ? 1 : 2);            \
                const void* g = a + (((size_t)vsel * BC + bcr) * MMAX + m) * NLAT \
                                  + k0_ + (ch4 ^ (bcr & 3)) * 8;                \
                gload16(g, Ab[buf] + wid * 1024 + i * 8192);                    \
            }                                                                   \
        }

    float4 wreg0, wreg1;
    #define WLOAD(kt)                                                           \
        {                                                                       \
            int ph_ = (kt) >> 3;                                                \
            int k0_ = ((kt) & 7) * 32;                                          \
            const float* wp = w + (((size_t)ph_ * MMAX + m) * LMAX + l0 + lB) * NLAT \
                                + k0_ + chB * 8;                                \
            wreg0 = *(const float4*)(wp);                                       \
            wreg1 = *(const float4*)(wp + 4);                                   \
        }
    #define BWRITE(buf)                                                         \
        {                                                                       \
            uint4 vv;                                                           \
            vv.x = bfpack2(wreg0.x, wreg0.y); vv.y = bfpack2(wreg0.z, wreg0.w); \
            vv.z = bfpack2(wreg1.x, wreg1.y); vv.w = bfpack2(wreg1.z, wreg1.w); \
            *(uint4*)(Bb[buf] + lB * 80 + chB * 16) = vv;                       \
        }
    #define MFMA_PHASE(ACC)                                                     \
        {                                                                       \
            bf16x8 bfr[4];                                                      \
            _Pragma("unroll")                                                   \
            for (int lt = 0; lt < 4; ++lt)                                      \
                bfr[lt] = *(const bf16x8*)(bb + (q * 64 + lt * 16 + r15) * 80 + hi * 16); \
            _Pragma("unroll")                                                   \
            for (int bt = 0; bt < 4; ++bt) {                                    \
                bf16x8 af = *(const bf16x8*)(ab + (o * 128 + h * 64 + bt * 16 + r15) * 64 \
                                               + ((hi * 16) ^ ((r15 & 3) << 4))); \
                _Pragma("unroll")                                               \
                for (int lt = 0; lt < 4; ++lt)                                  \
                    ACC[bt][lt] = __builtin_amdgcn_mfma_f32_16x16x32_bf16(af, bfr[lt], ACC[bt][lt], 0, 0, 0); \
            }                                                                   \
        }

    STAGE_A(0, 0);
    WLOAD(0);
    __syncthreads();
    BWRITE(0);

    for (int kt2 = 0; kt2 < 16; ++kt2) {
        int cur = kt2 & 1;
        if (kt2 < 15) WLOAD(kt2 + 1);
        __syncthreads();
        if (kt2 < 15) STAGE_A(cur ^ 1, kt2 + 1);

        const unsigned char* bb = Bb[cur];
        const unsigned char* ab = Ab[cur];
        if (kt2 < 8) MFMA_PHASE(accLo) else MFMA_PHASE(accHi);

        if (kt2 < 15) BWRITE(cur ^ 1);
    }

    #pragma unroll
    for (int bt = 0; bt < 4; ++bt) {
        #pragma unroll
        for (int lt = 0; lt < 4; ++lt) {
            #pragma unroll
            for (int j = 0; j < 4; ++j) {
                int bc = h * 64 + bt * 16 + hi * 4 + j;
                int l  = l0 + q * 64 + lt * 16 + r15;
                float lo = accLo[bt][lt][j];
                float hh = accHi[bt][lt][j];
                float val = (o == 0) ? (lo - hh) : (0.0f - (lo + hh));
                if (MODE == 0) {
                    __hip_bfloat16* outs = (__hip_bfloat16*)outv;
                    outs[(((size_t)m * 2 + o) * BC + bc) * LMAX + l] = __float2bfloat16(val);
                } else {
                    float* out = (float*)outv;
                    out[(((size_t)bc * 2 + o) * LMAX + l) * MMAX + m] = val;
                }
            }
        }
    }
    #undef STAGE_A
    #undef WLOAD
    #undef BWRITE
    #undef MFMA_PHASE
}

// ---------------------------------------------------------------------------
// K3: transpose outs[m][o][bc][l] bf16 -> out[bc][o][l][m] fp32 (validated).
// ---------------------------------------------------------------------------
__global__ __launch_bounds__(256) void transpose_out(const unsigned short* __restrict__ outs,
                                                     float* __restrict__ out)
{
    __shared__ float tile[32][65];
    int mt = blockIdx.x;            // 0..8
    int lt = blockIdx.y;            // 0..3
    int z  = blockIdx.z;            // 0..255
    int bc = z >> 1, o = z & 1;
    int t = threadIdx.x;

    {
        int r = t >> 3, c0 = (t & 7) * 8;
        int mm = mt * 32 + r;
        if (mm < MMAX) {
            const unsigned short* src = outs + (((size_t)mm * 2 + o) * BC + bc) * LMAX + lt * 64 + c0;
            uint4 v = *(const uint4*)src;
            const unsigned short* u = (const unsigned short*)&v;
            #pragma unroll
            for (int i = 0; i < 8; ++i)
                tile[r][c0 + i] = __bfloat162float(__builtin_bit_cast(__hip_bfloat16, u[i]));
        }
    }
    __syncthreads();
    {
        int l = t >> 2, mc = (t & 3) * 8;
        float* dst = out + (((size_t)bc * 2 + o) * LMAX + lt * 64 + l) * MMAX + mt * 32 + mc;
        #pragma unroll
        for (int i = 0; i < 8; ++i) {
            int mm = mt * 32 + mc + i;
            if (mm < MMAX) dst[i] = tile[mc + i][l];
        }
    }
}

// ---------------------------------------------------------------------------
// Legacy proven path (round 9) — fallback for small ws.
// ---------------------------------------------------------------------------
#define PER_BC ((size_t)4 * MMAX * NLAT * sizeof(__hip_bfloat16))

__global__ __launch_bounds__(256) void dft_legacy(const float* __restrict__ x,
                                                  __hip_bfloat16* __restrict__ a,
                                                  int bc0, int nbc)
{
    __shared__ float  xs[512];
    __shared__ float2 tw[512];
    int t = threadIdx.x;
    int b = blockIdx.x;
    int lat = b & (NLAT - 1);
    int comp = (b >> 8) & 1;
    int bcl = b >> 9;
    int bc = bc0 + bcl;
    const float* xr = x + (((size_t)bc * 2 + comp) * NLAT + lat) * NLON;
    for (int j = t; j < 512; j += 256) {
        xs[j] = xr[j];
        float ang = -6.283185307179586f * (float)j / 512.0f;
        float sn, cs; sincosf(ang, &sn, &cs);
        tw[j] = make_float2(cs, sn);
    }
    __syncthreads();
    const float scale = 6.283185307179586f / 512.0f;
    size_t VS = (size_t)nbc * MMAX * NLAT;
    __hip_bfloat16* p0 = a + (size_t)(comp * 2) * VS + (size_t)bcl * MMAX * NLAT + lat;
    __hip_bfloat16* p1 = p0 + VS;
    for (int m = t; m < MMAX; m += 256) {
        float accr = 0.f, acci = 0.f;
        int j = 0;
        for (int n = 0; n < 512; ++n) {
            float xv = xs[n]; float2 wv = tw[j];
            accr += xv * wv.x; acci += xv * wv.y;
            j = (j + m) & 511;
        }
        p0[(size_t)m * NLAT] = __float2bfloat16(accr * scale);
        p1[(size_t)m * NLAT] = __float2bfloat16(acci * scale);
    }
}

__global__ __launch_bounds__(256) void contract_legacy(const __hip_bfloat16* __restrict__ a,
                                                       const float* __restrict__ w,
                                                       float* __restrict__ out,
                                                       int bc0, int nbc)
{
    __shared__ float w0s[16][NLAT + 1];
    __shared__ float w1s[16][NLAT + 1];
    __shared__ float as[4][4][NLAT + 1];
    __shared__ float2 red2[256];
    int tid = threadIdx.x;
    int m = blockIdx.x, l0 = blockIdx.y * 16, bct = blockIdx.z * 4;
    const float* w0g = w + ((size_t)m * LMAX + l0) * NLAT;
    const float* w1g = w0g + (size_t)MMAX * LMAX * NLAT;
    for (int idx = tid; idx < 16 * NLAT; idx += 256) {
        int l = idx >> 8, k = idx & 255;
        w0s[l][k] = w0g[(size_t)l * NLAT + k];
        w1s[l][k] = w1g[(size_t)l * NLAT + k];
    }
    size_t VS = (size_t)nbc * MMAX * NLAT;
    for (int idx = tid; idx < 4 * 4 * NLAT; idx += 256) {
        int v = idx >> 10, bl = (idx >> 8) & 3, k = idx & 255;
        int bls = bct + bl; if (bls > nbc - 1) bls = nbc - 1;
        as[v][bl][k] = __bfloat162float(a[(size_t)v * VS + ((size_t)bls * MMAX + m) * NLAT + k]);
    }
    __syncthreads();
    int l = tid & 15, b = (tid >> 4) & 3, kseg = tid >> 6;
    float acc0 = 0.f, acc2 = 0.f;
    int kbeg = kseg * 64;
    #pragma unroll 8
    for (int k = kbeg; k < kbeg + 64; ++k) {
        float tr = as[0][b][k], ti = as[1][b][k], pr = as[2][b][k], pi = as[3][b][k];
        float w0 = w0s[l][k], w1 = w1s[l][k];
        acc0 += tr * w0 - pi * w1;
        acc2 -= ti * w1 + pr * w0;
    }
    red2[tid] = make_float2(acc0, acc2);
    __syncthreads();
    if (kseg == 0 && (bct + b) < nbc) {
        #pragma unroll
        for (int s = 1; s < 4; ++s) {
            float2 r = red2[tid + 64 * s];
            acc0 += r.x; acc2 += r.y;
        }
        int bc = bc0 + bct + b;
        out[(((size_t)bc * 2 + 0) * LMAX + (l0 + l)) * MMAX + m] = acc0;
        out[(((size_t)bc * 2 + 1) * LMAX + (l0 + l)) * MMAX + m] = acc2;
    }
}

extern "C" void kernel_launch(void* const* d_in, const int* in_sizes, int n_in,
                              void* d_out, int out_size, void* d_ws, size_t ws_size,
                              hipStream_t stream)
{
    const float* x = (const float*)d_in[0];
    const float* w = (const float*)d_in[1];
    if (n_in >= 2) {
        long long s0 = (long long)in_sizes[0];
        if (s0 == (long long)W_ELEMS || s0 == W_BYTES) {
            w = (const float*)d_in[0];
            x = (const float*)d_in[1];
        }
    }
    float* out = (float*)d_out;

    if (ws_size >= F_BYTES + A_BYTES) {
        unsigned short* F = (unsigned short*)d_ws;
        unsigned short* a = (unsigned short*)((char*)d_ws + F_BYTES);
        hipLaunchKernelGGL(f_init, dim3(FM, 2), dim3(256), 0, stream, F);
        hipLaunchKernelGGL(dft_mfma, dim3(256, 2), dim3(512), 0, stream, x, F, a);
        if (ws_size >= F_BYTES + A_BYTES + OUTS_BYTES) {
            unsigned short* outs = (unsigned short*)((char*)d_ws + F_BYTES + A_BYTES);
            hipLaunchKernelGGL((contract_mfma<0>), dim3(MMAX, 2), dim3(512), 0, stream,
                               a, w, (void*)outs);
            hipLaunchKernelGGL(transpose_out, dim3(9, 4, 256), dim3(256), 0, stream,
                               outs, out);
        } else {
            hipLaunchKernelGGL((contract_mfma<1>), dim3(MMAX, 2), dim3(512), 0, stream,
                               a, w, (void*)out);
        }
    } else {
        __hip_bfloat16* a = (__hip_bfloat16*)d_ws;
        int nbc = 1;
        for (int c = 128; c >= 1; c >>= 1)
            if (PER_BC * (size_t)c <= ws_size) { nbc = c; break; }
        int nchunks = BC / nbc;
        for (int cc = 0; cc < nchunks; ++cc) {
            int bc0 = cc * nbc;
            hipLaunchKernelGGL(dft_legacy, dim3(nbc * 2 * NLAT), dim3(256), 0, stream,
                               x, a, bc0, nbc);
            hipLaunchKernelGGL(contract_legacy, dim3(MMAX, LMAX / 16, (nbc + 3) / 4),
                               dim3(256), 0, stream, a, w, out, bc0, nbc);
        }
    }
}